// Round 3
// baseline (268.470 us; speedup 1.0000x reference)
//
#include <hip/hip_runtime.h>

// Length_Regulate alignment matrix.
//   repeats = (int)(durations + 0.5)   [B, T], durations in [1,8) => repeats 1..8
//   ends = inclusive_cumsum(repeats); starts = ends - repeats
//   out[b, t, j] = 1.0f iff starts[j] <= t < ends[j]  (one-hot per (b,t) row)
//
// Model after 3 rounds: iteration time = 163us poison fill (fixed) + ~40us
// tiny-dispatch gaps (fixed) + my 268MB output write. Round-2's writer kept
// 16 dependent global loads of inv[] on the store path (~4.7 TB/s). This
// round: load-free store loop.
//   K1 (32 blocks): LDS scan -> inverse map inv[b][t] = one-hot column (or -1).
//   K2 (1024 blocks): per block stage 128 ints of inv into LDS (one coalesced
//       load), then 256KB of pure non-temporal float4 stores; the only
//       per-iteration non-store op is a broadcast LDS read (no bank conflict:
//       r is wave-uniform). Structurally == fillBufferAligned (6.5 TB/s).

#define T_TEXT 512
#define RB2 128               // rows per writer block -> 256 KB tile
#define WTHR 256

typedef float f32x4 __attribute__((ext_vector_type(4)));

// ---- K1: scan + inverse map ----
__global__ __launch_bounds__(T_TEXT) void lr_scan_inv(
        const float* __restrict__ dur,
        int* __restrict__ inv,
        int max_len) {
    __shared__ int s[T_TEXT];
    const int b = blockIdx.x;
    const int tid = threadIdx.x;

    const int rep = (int)(dur[b * T_TEXT + tid] + 0.5f);  // same FP ops as ref
    s[tid] = rep;
    __syncthreads();
    for (int off = 1; off < T_TEXT; off <<= 1) {          // Hillis-Steele
        int v = s[tid];
        int add = (tid >= off) ? s[tid - off] : 0;
        __syncthreads();
        s[tid] = v + add;
        __syncthreads();
    }
    int end = s[tid];
    int start = end - rep;
    int total = s[T_TEXT - 1];
    if (end > max_len) end = max_len;

    int* invb = inv + b * max_len;
    for (int t = start; t < end; ++t) invb[t] = tid;      // <=8 stores/thread
    for (int t = total + tid; t < max_len; t += T_TEXT) invb[t] = -1;
}

// ---- K2: load-free streaming writer ----
__global__ __launch_bounds__(WTHR) void lr_fill2(
        const int* __restrict__ inv,
        float* __restrict__ out,
        int max_len) {
    __shared__ int s_j[RB2];
    const int b  = blockIdx.y;
    const int t0 = blockIdx.x * RB2;
    const int tid = threadIdx.x;

    const int rows = (max_len - t0 < RB2) ? (max_len - t0) : RB2;
    if (tid < rows) s_j[tid] = inv[b * max_len + t0 + tid];
    __syncthreads();

    f32x4* outv = (f32x4*)(out + ((size_t)b * max_len + t0) * T_TEXT);
    const int nvec = rows * (T_TEXT / 4);     // 16384 float4 = 256 KB

    #pragma unroll 8
    for (int f = tid; f < nvec; f += WTHR) {
        int r = f >> 7;               // wave-uniform (64-aligned span within 128)
        int c = (f & 127) << 2;       // starting column of this float4
        int j = s_j[r];               // broadcast LDS read, ~6 cyc
        f32x4 v = (f32x4)(0.f);
        int d = j - c;
        if ((unsigned)d < 4u) v[d] = 1.0f;
        __builtin_nontemporal_store(v, &outv[f]);
    }
}

// ---- fallback path (workspace too small): memset + scatter ----
__global__ __launch_bounds__(T_TEXT) void lr_scan_scatter(
        const float* __restrict__ dur,
        float* __restrict__ out,
        int max_len) {
    __shared__ int s[T_TEXT];
    const int b = blockIdx.x;
    const int tid = threadIdx.x;
    const int rep = (int)(dur[b * T_TEXT + tid] + 0.5f);
    s[tid] = rep;
    __syncthreads();
    for (int off = 1; off < T_TEXT; off <<= 1) {
        int v = s[tid];
        int add = (tid >= off) ? s[tid - off] : 0;
        __syncthreads();
        s[tid] = v + add;
        __syncthreads();
    }
    int end = s[tid];
    int start = end - rep;
    if (end > max_len) end = max_len;
    float* col = out + ((size_t)b * max_len) * T_TEXT + tid;
    for (int t = start; t < end; ++t) col[(size_t)t * T_TEXT] = 1.0f;
}

extern "C" void kernel_launch(void* const* d_in, const int* in_sizes, int n_in,
                              void* d_out, int out_size, void* d_ws, size_t ws_size,
                              hipStream_t stream) {
    const float* dur = (const float*)d_in[0];
    float* out = (float*)d_out;

    const int BT = in_sizes[0];           // B * T_TEXT elements (16384)
    const int B = BT / T_TEXT;            // 32
    const int max_len = out_size / BT;    // 4096

    const size_t inv_bytes = (size_t)B * max_len * sizeof(int);  // 512 KB

    if (ws_size >= inv_bytes) {
        int* inv = (int*)d_ws;
        lr_scan_inv<<<B, T_TEXT, 0, stream>>>(dur, inv, max_len);
        dim3 grid((max_len + RB2 - 1) / RB2, B);
        lr_fill2<<<grid, WTHR, 0, stream>>>(inv, out, max_len);
    } else {
        hipMemsetAsync(d_out, 0, (size_t)out_size * sizeof(float), stream);
        lr_scan_scatter<<<B, T_TEXT, 0, stream>>>(dur, out, max_len);
    }
}

// Round 4
// 253.255 us; speedup vs baseline: 1.0601x; 1.0601x over previous
//
#include <hip/hip_runtime.h>

// Length_Regulate alignment matrix, one-hot formulation (round-1 structure,
// which measured best at 253.9us; rounds 2-3 custom streaming writers were
// 5-8us slower because hand-written store streams top out ~4.7 TB/s vs the
// runtime fillBufferAligned's measured 6.5 TB/s).
//
//   repeats = (int)(durations + 0.5)   [B, T], durations in [1,8) => 1..8
//   ends = inclusive_cumsum(repeats); starts = ends - repeats
//   out[b, t, j] = 1.0f iff starts[j] <= t < ends[j]
//
// Structure:
//   1) hipMemsetAsync(out, 0): 268 MB at the measured fill roofline (~41us).
//   2) one 32-block fused scan+scatter kernel (~4us): wave-shuffle scan
//      (6 shfl_up steps + 1 barrier for 8 wave partials, vs round-1's
//      18-barrier Hillis-Steele), then <=8 strided 4B stores per thread
//      writing the ~74K ones.
// Floor arithmetic: poison fill ~165 + harness gaps ~40 + memset 41 +
// scatter ~4 ~= 250us. If this round lands >=253, we are at the harness
// floor and the next call is ROOFLINE.

#define T_TEXT 512

__global__ __launch_bounds__(T_TEXT) void lr_scan_scatter(
        const float* __restrict__ dur,
        float* __restrict__ out,
        int max_len) {
    __shared__ int wsum[8];
    const int b = blockIdx.x;
    const int tid = threadIdx.x;          // 512 threads = 8 waves
    const int lane = tid & 63;
    const int wave = tid >> 6;

    // Same FP op sequence as reference: truncate(d + 0.5), d > 0.
    const int rep = (int)(dur[b * T_TEXT + tid] + 0.5f);

    // Inclusive scan within each 64-lane wave via shuffles (no LDS, no barrier).
    int v = rep;
    #pragma unroll
    for (int off = 1; off < 64; off <<= 1) {
        int n = __shfl_up(v, off, 64);
        if (lane >= off) v += n;
    }
    if (lane == 63) wsum[wave] = v;       // per-wave total
    __syncthreads();

    // Add exclusive prefix of preceding waves' totals (8 LDS broadcasts).
    int prefix = 0;
    #pragma unroll
    for (int w = 0; w < 7; ++w) {
        int ws = wsum[w];
        if (w < wave) prefix += ws;
    }

    int end = prefix + v;                 // inclusive cumsum
    int start = end - rep;
    if (end > max_len) end = max_len;     // defensive clamp (sum ~2300 < 4096)
    if (start > max_len) start = max_len;

    // Column j = tid of batch b: rows [start, end) get 1.0f.
    float* col = out + ((size_t)b * max_len) * T_TEXT + tid;
    for (int t = start; t < end; ++t) {
        col[(size_t)t * T_TEXT] = 1.0f;   // <=8 stores/thread, stride 2KB
    }
}

extern "C" void kernel_launch(void* const* d_in, const int* in_sizes, int n_in,
                              void* d_out, int out_size, void* d_ws, size_t ws_size,
                              hipStream_t stream) {
    const float* dur = (const float*)d_in[0];
    float* out = (float*)d_out;

    const int BT = in_sizes[0];           // B * T_TEXT elements (16384)
    const int B = BT / T_TEXT;            // 32
    const int max_len = out_size / BT;    // 4096

    // Bulk zero at the measured fill roofline (6.5 TB/s, per rocprof).
    hipMemsetAsync(d_out, 0, (size_t)out_size * sizeof(float), stream);

    // Scatter the ~74K ones.
    lr_scan_scatter<<<B, T_TEXT, 0, stream>>>(dur, out, max_len);
}